// Round 12
// baseline (175.510 us; speedup 1.0000x reference)
//
#include <hip/hip_runtime.h>

typedef __attribute__((ext_vector_type(8))) short short8;
typedef __attribute__((ext_vector_type(4))) float f32x4;

#define IN_DIM 256
#define OUT_DIM 256
#define NB 16                 // padded basis count (13 real + 3 zero)
#define KDIM (IN_DIM * NB)    // 4096
#define TM 64
#define TN 64
#define STEPS 32              // 8 i-values per step (BK = 128 k)

__device__ __forceinline__ unsigned short f2bf(float f) {
  union { float f; unsigned int u; } v; v.f = f;
  unsigned int r = v.u + 0x7fffu + ((v.u >> 16) & 1u);  // RNE
  return (unsigned short)(r >> 16);
}

// --- prep: BmT[o][i*16+n] = bf16( sum_e softmax(gating[i,o,:])[e] * coeff[e,n] )
__global__ __launch_bounds__(256) void kan_prep(const float* __restrict__ coeff,
                                                const float* __restrict__ gw,
                                                unsigned short* __restrict__ BmT) {
  __shared__ float csh[104];
  __shared__ unsigned short tile[16][256];   // [o_loc][il*16+n]
  const int t = threadIdx.x;
  if (t < 104) csh[t] = coeff[t];
  __syncthreads();
  const int otile = blockIdx.x, itile = blockIdx.y;
  const int il = t >> 4, ol = t & 15;
  const int i = itile * 16 + il;
  const int o = otile * 16 + ol;
  const float* g = gw + (size_t)(i * OUT_DIM + o) * 8;
  float4 g0 = *(const float4*)g;
  float4 g1 = *(const float4*)(g + 4);
  float ge[8] = {g0.x, g0.y, g0.z, g0.w, g1.x, g1.y, g1.z, g1.w};
  float mx = ge[0];
#pragma unroll
  for (int e = 1; e < 8; ++e) mx = fmaxf(mx, ge[e]);
  float p[8]; float s = 0.f;
#pragma unroll
  for (int e = 0; e < 8; ++e) { p[e] = __expf(ge[e] - mx); s += p[e]; }
  const float inv = 1.0f / s;
  unsigned short row[16];
#pragma unroll
  for (int n = 0; n < 13; ++n) {
    float w = 0.f;
#pragma unroll
    for (int e = 0; e < 8; ++e) w += p[e] * csh[e * 13 + n];
    row[n] = f2bf(w * inv);
  }
  row[13] = 0; row[14] = 0; row[15] = 0;
  int4* dst = (int4*)&tile[ol][il * 16];
  dst[0] = *(const int4*)&row[0];
  dst[1] = *(const int4*)&row[8];
  __syncthreads();
  const int oo = t >> 4, ck = t & 15;
  int4 v0 = *(const int4*)&tile[oo][ck * 16];
  int4 v1 = *(const int4*)&tile[oo][ck * 16 + 8];
  int4* out4 = (int4*)(BmT + (size_t)(otile * 16 + oo) * KDIM + itile * 256 + ck * 16);
  out4[0] = v0;
  out4[1] = v1;
}

// spline granule: bf16 basis slots [8g, 8g+8) for value xv, as a ready MFMA A-frag.
__device__ __forceinline__ short8 spline_granule(float xv, int g) {
  float xc = fminf(fmaxf(xv, -1.0f), 1.0f - 1e-6f);
  float u = (xc + 1.0f) * 5.0f;            // h = 0.2
  int c = (int)u;
  c = c > 9 ? 9 : (c < 0 ? 0 : c);
  float tt = u - (float)c;
  float omt = 1.0f - tt;
  float t2 = tt * tt, t3 = t2 * tt;
  float b0 = omt * omt * omt * (1.0f / 6.0f);
  float b1 = (3.0f * t3 - 6.0f * t2 + 4.0f) * (1.0f / 6.0f);
  float b2 = (-3.0f * t3 + 3.0f * t2 + 3.0f * tt + 1.0f) * (1.0f / 6.0f);
  float b3 = t3 * (1.0f / 6.0f);
  unsigned h0 = f2bf(b0), h1 = f2bf(b1), h2 = f2bf(b2), h3 = f2bf(b3);
  const int a = c >> 1;
  const bool odd = (c & 1) != 0;
  unsigned A0 = odd ? (h0 << 16) : (h0 | (h1 << 16));
  unsigned A1 = odd ? (h1 | (h2 << 16)) : (h2 | (h3 << 16));
  unsigned A2 = odd ? h3 : 0u;
  union { unsigned u[4]; short8 s; } r;
  const int base = g * 4;
#pragma unroll
  for (int j = 0; j < 4; ++j) {
    const int jj = base + j;
    unsigned v = (jj == a) ? A0 : 0u;
    v = (jj == a + 1) ? A1 : v;
    v = (jj == a + 2) ? A2 : v;
    r.u[j] = v;
  }
  return r.s;
}

struct XS { float4 r0l, r0h, r1l, r1h; };        // two rows x 8 x-values
struct BS { short8 v[4][2]; };                    // [ks][nf] B fragments

__device__ __forceinline__ void load_x(const float* xr0, const float* xr1, int s, XS& o) {
  const int sc = (s < STEPS) ? s : STEPS - 1;
  o.r0l = *(const float4*)(xr0 + sc * 8);
  o.r0h = *(const float4*)(xr0 + sc * 8 + 4);
  o.r1l = *(const float4*)(xr1 + sc * 8);
  o.r1h = *(const float4*)(xr1 + sc * 8 + 4);
}
__device__ __forceinline__ void load_b(const unsigned short* bp0, const unsigned short* bp1,
                                       int s, BS& o) {
  const int sc = (s < STEPS) ? s : STEPS - 1;
#pragma unroll
  for (int ks = 0; ks < 4; ++ks) {
    o.v[ks][0] = *(const short8*)(bp0 + sc * 128 + ks * 32);
    o.v[ks][1] = *(const short8*)(bp1 + sc * 128 + ks * 32);
  }
}

// --- fused basis + GEMM, ZERO-sync design:
// No LDS, no barriers, no DMA. Each lane builds its MFMA A-fragment entirely
// in registers: for frag slice ks, lane (rl=l&15, qd=l>>4) needs basis slots
// n in [8*(qd&1), +8) of spline(x[row][i]), i = 8s + 2ks + (qd>>1) — ONE
// per-lane eval yields the lane's whole 8-elem fragment (2x redundancy across
// qd pairs buys zero communication). B-frags are per-lane contiguous 16 B of
// L2-resident BmT, prefetched one full step ahead into registers (compiler
// auto-vmcnt before first use = only wait in the kernel). x prefetched same.
// TM=64 x TN=64, 4 waves (2M x 2N), grid (128,4)=512 blocks = 2/CU.
__global__ __launch_bounds__(256, 2) void kan_gemm(const float* __restrict__ x,
                                                   const unsigned short* __restrict__ BmT,
                                                   float* __restrict__ out) {
  const int t = threadIdx.x;
  const int lane = t & 63;
  const int wave = t >> 6;
  const int wm = wave >> 1, wn = wave & 1;     // 2M x 2N waves, 32x32 out each
  const int mb = blockIdx.x * TM;
  const int ob = blockIdx.y * TN;
  const int rl = lane & 15, qd = lane >> 4;
  const int qdh = qd >> 1, qg = qd & 1;

  const float* xr0 = x + (size_t)(mb + wm * 32 + rl) * IN_DIM;
  const float* xr1 = xr0 + 16 * IN_DIM;
  const unsigned short* bp0 = BmT + (size_t)(ob + wn * 32 + rl) * KDIM + qd * 8;
  const unsigned short* bp1 = bp0 + (size_t)16 * KDIM;

  f32x4 acc[2][2];
#pragma unroll
  for (int a = 0; a < 2; ++a)
#pragma unroll
    for (int b = 0; b < 2; ++b) acc[a][b] = (f32x4){0.f, 0.f, 0.f, 0.f};

  XS xA, xB;
  BS bA, bB;
  load_x(xr0, xr1, 0, xA);
  load_b(bp0, bp1, 0, bA);

#pragma unroll 1
  for (int s = 0; s < STEPS; s += 2) {
    // ---- even step: consume A-sets, prefetch into B-sets
    load_b(bp0, bp1, s + 1, bB);
    load_x(xr0, xr1, s + 1, xB);
#pragma unroll
    for (int ks = 0; ks < 4; ++ks) {
      const float c0 = (ks == 0) ? (qdh ? xA.r0l.y : xA.r0l.x)
                     : (ks == 1) ? (qdh ? xA.r0l.w : xA.r0l.z)
                     : (ks == 2) ? (qdh ? xA.r0h.y : xA.r0h.x)
                                 : (qdh ? xA.r0h.w : xA.r0h.z);
      const float c1 = (ks == 0) ? (qdh ? xA.r1l.y : xA.r1l.x)
                     : (ks == 1) ? (qdh ? xA.r1l.w : xA.r1l.z)
                     : (ks == 2) ? (qdh ? xA.r1h.y : xA.r1h.x)
                                 : (qdh ? xA.r1h.w : xA.r1h.z);
      const short8 a0 = spline_granule(c0, qg);
      const short8 a1 = spline_granule(c1, qg);
      acc[0][0] = __builtin_amdgcn_mfma_f32_16x16x32_bf16(a0, bA.v[ks][0], acc[0][0], 0, 0, 0);
      acc[0][1] = __builtin_amdgcn_mfma_f32_16x16x32_bf16(a0, bA.v[ks][1], acc[0][1], 0, 0, 0);
      acc[1][0] = __builtin_amdgcn_mfma_f32_16x16x32_bf16(a1, bA.v[ks][0], acc[1][0], 0, 0, 0);
      acc[1][1] = __builtin_amdgcn_mfma_f32_16x16x32_bf16(a1, bA.v[ks][1], acc[1][1], 0, 0, 0);
    }
    // ---- odd step: consume B-sets, prefetch into A-sets
    load_b(bp0, bp1, s + 2, bA);
    load_x(xr0, xr1, s + 2, xA);
#pragma unroll
    for (int ks = 0; ks < 4; ++ks) {
      const float c0 = (ks == 0) ? (qdh ? xB.r0l.y : xB.r0l.x)
                     : (ks == 1) ? (qdh ? xB.r0l.w : xB.r0l.z)
                     : (ks == 2) ? (qdh ? xB.r0h.y : xB.r0h.x)
                                 : (qdh ? xB.r0h.w : xB.r0h.z);
      const float c1 = (ks == 0) ? (qdh ? xB.r1l.y : xB.r1l.x)
                     : (ks == 1) ? (qdh ? xB.r1l.w : xB.r1l.z)
                     : (ks == 2) ? (qdh ? xB.r1h.y : xB.r1h.x)
                                 : (qdh ? xB.r1h.w : xB.r1h.z);
      const short8 a0 = spline_granule(c0, qg);
      const short8 a1 = spline_granule(c1, qg);
      acc[0][0] = __builtin_amdgcn_mfma_f32_16x16x32_bf16(a0, bB.v[ks][0], acc[0][0], 0, 0, 0);
      acc[0][1] = __builtin_amdgcn_mfma_f32_16x16x32_bf16(a0, bB.v[ks][1], acc[0][1], 0, 0, 0);
      acc[1][0] = __builtin_amdgcn_mfma_f32_16x16x32_bf16(a1, bB.v[ks][0], acc[1][0], 0, 0, 0);
      acc[1][1] = __builtin_amdgcn_mfma_f32_16x16x32_bf16(a1, bB.v[ks][1], acc[1][1], 0, 0, 0);
    }
  }

  // epilogue: direct coalesced stores (each output element written exactly once)
#pragma unroll
  for (int mf = 0; mf < 2; ++mf)
#pragma unroll
    for (int nf = 0; nf < 2; ++nf)
#pragma unroll
      for (int q = 0; q < 4; ++q) {
        int row = mb + wm * 32 + mf * 16 + qd * 4 + q;
        int col = ob + wn * 32 + nf * 16 + rl;
        out[(size_t)row * OUT_DIM + col] = acc[mf][nf][q];
      }
}

extern "C" void kernel_launch(void* const* d_in, const int* in_sizes, int n_in,
                              void* d_out, int out_size, void* d_ws, size_t ws_size,
                              hipStream_t stream) {
  const float* x     = (const float*)d_in[0];   // (4,2048,256) f32
  const float* coeff = (const float*)d_in[1];   // (8,13) f32
  const float* gw    = (const float*)d_in[2];   // (256,256,8) f32
  float* out = (float*)d_out;                   // (4,2048,256) f32
  unsigned short* BmT = (unsigned short*)d_ws;  // 256 x 4096 bf16 = 2 MB

  kan_prep<<<dim3(16, 16), dim3(256), 0, stream>>>(coeff, gw, BmT);
  dim3 grid(8192 / TM, OUT_DIM / TN);
  kan_gemm<<<grid, dim3(256), 0, stream>>>(x, BmT, out);
}